// Round 12
// baseline (5752.740 us; speedup 1.0000x reference)
//
#include <hip/hip_runtime.h>
#include <cstdint>
#include <cstddef>

#define H      128
#define IN_    12
#define GATES  512   // 4*H
#define B_     256
#define T_     2048
#define TCMAX  512
#define TT     64    // gemm time-tile

#define REP32(M) M(0) M(1) M(2) M(3) M(4) M(5) M(6) M(7) M(8) M(9) M(10) M(11) \
  M(12) M(13) M(14) M(15) M(16) M(17) M(18) M(19) M(20) M(21) M(22) M(23) \
  M(24) M(25) M(26) M(27) M(28) M(29) M(30) M(31)

// broadcast lane l's float to all lanes via SGPR (VALU pipe, not DS pipe)
#define RLF(v, l) __int_as_float(__builtin_amdgcn_readlane(__float_as_int(v), (l)))

__device__ __forceinline__ float sigmoidf_(float x) {
    return 1.f / (1.f + __expf(-x));
}
__device__ __forceinline__ float tanhf_(float x) {
    return 2.f / (1.f + __expf(-2.f * x)) - 1.f;
}
__device__ __forceinline__ float dot4f(float4 w, float4 h, float a) {
    return fmaf(w.x, h.x, fmaf(w.y, h.y, fmaf(w.z, h.z, fmaf(w.w, h.w, a))));
}

// ======================= LSTM scan (both layers) =======================
// 1024 thr = 16 waves, ONE block/CU (pair experiment proved no co-residency).
// waves_per_eu(4,4) -> 128-VGPR budget so the 16 float4 weights live in ARCH
// VGPRs (rounds 4-10 silently kept them in AGPRs: VGPR_Count=56, one
// accvgpr_read per FMA). Thread (ks=tid>>7, q=tid&127) owns the 4 GATE rows
// of hidden q (q, q+128, q+256, q+384), k-window [16ks,16ks+16).
// h delivery: ONE ds_read_b64 per lane (lane l holds h[2l],h[2l+1]) + 16
// v_readlane (uniform lane idx via readfirstlane) -> DS reads 64->16/step.
// Partials: one ds_write_b128 (i,f,g,o) at [ks][q]; phase-2 reads 8
// conflict-free ds_read_b128 at [m][tid]  (round-4 layout: 2.5e7 conflicts).
// (Weight frag names use LETTER suffixes: w##i##2.x pasted w0 against the
// pp-number "2.x" -> invalid token, round-11 compile fail.)
template<bool IS_L0>
__device__ __forceinline__ void scan_body(
    int b, const float* __restrict__ x_or_gx, const float* __restrict__ Wih,
    const float* __restrict__ Whh, const float* __restrict__ bih,
    const float* __restrict__ bhh, float* __restrict__ hs0,
    float* __restrict__ state, int tc, int chunk, float* smem)
{
    const int tid  = threadIdx.x;
    const int lane = tid & 63;
    const int q    = tid & 127;
    const int ksu  = __builtin_amdgcn_readfirstlane(threadIdx.x >> 7); // 0..7 uniform
    const int lb   = 8 * ksu;                                          // readlane base

    float* sh_part = smem;                  // 8*512 floats = 16 KB
    float* sh_h    = smem + 8 * 512;        // 128
    float* sh_x    = sh_h + H;              // L0: tc*12

    // resident W_hh fragment: gate rows i*128+q, cols 16ksu..16ksu+16
#define LOADW(i) \
    const float4* wr##i = (const float4*)(Whh + (size_t)(i * H + q) * H + 16 * ksu); \
    float4 w##i##a = wr##i[0], w##i##b = wr##i[1], w##i##c = wr##i[2], w##i##d = wr##i[3];
    LOADW(0) LOADW(1) LOADW(2) LOADW(3)
#undef LOADW

    // L0: x-proj weights for ks 1..3 (4 floats per gate row)
    float4 wx0 = {0,0,0,0}, wx1 = {0,0,0,0}, wx2 = {0,0,0,0}, wx3 = {0,0,0,0};
    if constexpr (IS_L0) {
        if (ksu >= 1 && ksu <= 3) {
            wx0 = *(const float4*)(Wih + (size_t)(0 * H + q) * IN_ + 4 * (ksu - 1));
            wx1 = *(const float4*)(Wih + (size_t)(1 * H + q) * IN_ + 4 * (ksu - 1));
            wx2 = *(const float4*)(Wih + (size_t)(2 * H + q) * IN_ + 4 * (ksu - 1));
            wx3 = *(const float4*)(Wih + (size_t)(3 * H + q) * IN_ + 4 * (ksu - 1));
        }
        const float* xs = x_or_gx + ((size_t)b * T_ + (size_t)chunk * tc) * IN_;
        for (int i = tid; i < tc * IN_; i += 1024) sh_x[i] = xs[i];
    }

    // epilogue-thread state (tid<128)
    float bias0 = 0, bias1 = 0, bias2 = 0, bias3 = 0;
    float cur0 = 0, cur1 = 0, cur2 = 0, cur3 = 0;
    float hreg = 0.f, creg = 0.f;
    const float* gxb = nullptr;
    if constexpr (!IS_L0) gxb = x_or_gx + (size_t)b * tc * GATES;

    if (tid < H) {
        if constexpr (IS_L0) {
            bias0 = bih[tid]       + bhh[tid];
            bias1 = bih[tid + 128] + bhh[tid + 128];
            bias2 = bih[tid + 256] + bhh[tid + 256];
            bias3 = bih[tid + 384] + bhh[tid + 384];
        } else {
            cur0 = gxb[tid]; cur1 = gxb[tid + 128];
            cur2 = gxb[tid + 256]; cur3 = gxb[tid + 384];
        }
        if (chunk) { hreg = state[b*2*H + tid]; creg = state[b*2*H + H + tid]; }
        sh_h[tid] = hreg;
    }
    __syncthreads();

    float* hs_out = nullptr;
    if constexpr (IS_L0) hs_out = hs0 + (size_t)b * tc * H;

    float4* sp4w = (float4*)sh_part;
    const float4* sp4 = (const float4*)sh_part;

    for (int t = 0; t < tc; ++t) {
        // ---- phase 1: partial dots (all 16 waves) ----
        float n0 = 0, n1 = 0, n2 = 0, n3 = 0;   // next-step gx prefetch (L1)
        if constexpr (!IS_L0) {
            if (tid < H) {
                int tn = (t + 1 < tc) ? t + 1 : t;
                const float* gp = gxb + (size_t)tn * GATES;
                n0 = gp[tid]; n1 = gp[tid + 128];
                n2 = gp[tid + 256]; n3 = gp[tid + 384];
            }
        }
        // one b64 LDS read/lane: whole h vector distributed across the wave
        float2 hl = ((const float2*)sh_h)[lane];
        // 16 readlane broadcasts of my k-window (VALU, not DS)
        float he0 = RLF(hl.x, lb+0), ho0 = RLF(hl.y, lb+0);
        float he1 = RLF(hl.x, lb+1), ho1 = RLF(hl.y, lb+1);
        float he2 = RLF(hl.x, lb+2), ho2 = RLF(hl.y, lb+2);
        float he3 = RLF(hl.x, lb+3), ho3 = RLF(hl.y, lb+3);
        float he4 = RLF(hl.x, lb+4), ho4 = RLF(hl.y, lb+4);
        float he5 = RLF(hl.x, lb+5), ho5 = RLF(hl.y, lb+5);
        float he6 = RLF(hl.x, lb+6), ho6 = RLF(hl.y, lb+6);
        float he7 = RLF(hl.x, lb+7), ho7 = RLF(hl.y, lb+7);

        float a0 = 0.f, a1 = 0.f, a2 = 0.f, a3 = 0.f;
#define ROWFMA(i) \
  a##i = fmaf(w##i##a.x, he0, fmaf(w##i##a.y, ho0, fmaf(w##i##a.z, he1, fmaf(w##i##a.w, ho1, a##i)))); \
  a##i = fmaf(w##i##b.x, he2, fmaf(w##i##b.y, ho2, fmaf(w##i##b.z, he3, fmaf(w##i##b.w, ho3, a##i)))); \
  a##i = fmaf(w##i##c.x, he4, fmaf(w##i##c.y, ho4, fmaf(w##i##c.z, he5, fmaf(w##i##c.w, ho5, a##i)))); \
  a##i = fmaf(w##i##d.x, he6, fmaf(w##i##d.y, ho6, fmaf(w##i##d.z, he7, fmaf(w##i##d.w, ho7, a##i))));
        ROWFMA(0) ROWFMA(1) ROWFMA(2) ROWFMA(3)
#undef ROWFMA
        if constexpr (IS_L0) {
            if (ksu >= 1 && ksu <= 3) {
                float4 xq = *(const float4*)(sh_x + t * IN_ + 4 * (ksu - 1));
                a0 = dot4f(wx0, xq, a0); a1 = dot4f(wx1, xq, a1);
                a2 = dot4f(wx2, xq, a2); a3 = dot4f(wx3, xq, a3);
            }
        }
        float4 av; av.x = a0; av.y = a1; av.z = a2; av.w = a3;
        sp4w[(ksu << 7) + q] = av;               // one ds_write_b128
        __syncthreads();

        // ---- phase 2: reduce + activate + state update (tid<128) ----
        if (tid < H) {
            float4 s = sp4[tid];
#define RQ(m) { float4 v = sp4[m * 128 + tid]; s.x += v.x; s.y += v.y; s.z += v.z; s.w += v.w; }
            RQ(1) RQ(2) RQ(3) RQ(4) RQ(5) RQ(6) RQ(7)
#undef RQ
            float gi, gf, gg, go;
            if constexpr (IS_L0) {
                gi = s.x + bias0; gf = s.y + bias1; gg = s.z + bias2; go = s.w + bias3;
            } else {
                gi = s.x + cur0; gf = s.y + cur1; gg = s.z + cur2; go = s.w + cur3;
                cur0 = n0; cur1 = n1; cur2 = n2; cur3 = n3;
            }
            creg = fmaf(sigmoidf_(gf), creg, sigmoidf_(gi) * tanhf_(gg));
            hreg = sigmoidf_(go) * tanhf_(creg);
            sh_h[tid] = hreg;
            if constexpr (IS_L0) hs_out[(size_t)t * H + tid] = hreg;
        }
        __syncthreads();
    }
    if (tid < H) { state[b*2*H + tid] = hreg; state[b*2*H + H + tid] = creg; }
}

__global__ __launch_bounds__(1024)
__attribute__((amdgpu_waves_per_eu(4, 4)))
void lstm_scan_l0(
    const float* __restrict__ x, const float* __restrict__ Wih,
    const float* __restrict__ Whh, const float* __restrict__ bih,
    const float* __restrict__ bhh, float* __restrict__ hs0,
    float* __restrict__ state, int tc, int chunk)
{
    extern __shared__ float smem[];
    scan_body<true>(blockIdx.x, x, Wih, Whh, bih, bhh, hs0, state, tc, chunk, smem);
}

__global__ __launch_bounds__(1024)
__attribute__((amdgpu_waves_per_eu(4, 4)))
void lstm_scan_l1(
    const float* __restrict__ gx, const float* __restrict__ Whh,
    float* __restrict__ state, int tc, int chunk)
{
    extern __shared__ float smem[];
    scan_body<false>(blockIdx.x, gx, nullptr, Whh, nullptr, nullptr,
                     nullptr, state, tc, chunk, smem);
}

// ======================= gx1 GEMM =======================
// Unchanged round-9 version (s_load h -> SGPR broadcast; ~165 us/chunk).
typedef __attribute__((ext_vector_type(16))) float f16x;

__global__ __launch_bounds__(512)
void gx1_gemm(const float* __restrict__ hs0, const float* __restrict__ Wih,
              const float* __restrict__ bih, const float* __restrict__ bhh,
              float* __restrict__ gx, int tc)
{
    const int b  = blockIdx.x;
    const int t0 = blockIdx.y * TT;
    const int g  = threadIdx.x;

#define LWG(j) float4 w##j = ((const float4*)(Wih + (size_t)g * H))[j];
    REP32(LWG)
#undef LWG
    const float biasg = bih[g] + bhh[g];

    const float* hp = hs0 + ((size_t)b * tc + t0) * H;      // block-uniform
    float* gxo = gx + ((size_t)b * tc + t0) * GATES + g;

    for (int t = 0; t < TT; ++t) {
        const float* hpt = hp + (size_t)t * H;
        float a0 = biasg, a1 = 0.f, a2 = 0.f, a3 = 0.f;

        f16x h0, h1, h2, h3;
        asm volatile(
            "s_load_dwordx16 %0, %4, 0x0\n\t"
            "s_load_dwordx16 %1, %4, 0x40\n\t"
            "s_load_dwordx16 %2, %4, 0x80\n\t"
            "s_load_dwordx16 %3, %4, 0xc0\n\t"
            "s_waitcnt lgkmcnt(0)"
            : "=s"(h0), "=s"(h1), "=s"(h2), "=s"(h3)
            : "s"(hpt));
#define Q4(hv, j0, j1, j2, j3) { \
        a0 = fmaf(w##j0.x, hv.s0, a0); a1 = fmaf(w##j0.y, hv.s1, a1); \
        a2 = fmaf(w##j0.z, hv.s2, a2); a3 = fmaf(w##j0.w, hv.s3, a3); \
        a0 = fmaf(w##j1.x, hv.s4, a0); a1 = fmaf(w##j1.y, hv.s5, a1); \
        a2 = fmaf(w##j1.z, hv.s6, a2); a3 = fmaf(w##j1.w, hv.s7, a3); \
        a0 = fmaf(w##j2.x, hv.s8, a0); a1 = fmaf(w##j2.y, hv.s9, a1); \
        a2 = fmaf(w##j2.z, hv.sa, a2); a3 = fmaf(w##j2.w, hv.sb, a3); \
        a0 = fmaf(w##j3.x, hv.sc, a0); a1 = fmaf(w##j3.y, hv.sd, a1); \
        a2 = fmaf(w##j3.z, hv.se, a2); a3 = fmaf(w##j3.w, hv.sf, a3); }
        Q4(h0, 0, 1, 2, 3)    Q4(h1, 4, 5, 6, 7)
        Q4(h2, 8, 9, 10, 11)  Q4(h3, 12, 13, 14, 15)

        asm volatile(
            "s_load_dwordx16 %0, %4, 0x100\n\t"
            "s_load_dwordx16 %1, %4, 0x140\n\t"
            "s_load_dwordx16 %2, %4, 0x180\n\t"
            "s_load_dwordx16 %3, %4, 0x1c0\n\t"
            "s_waitcnt lgkmcnt(0)"
            : "=s"(h0), "=s"(h1), "=s"(h2), "=s"(h3)
            : "s"(hpt));
        Q4(h0, 16, 17, 18, 19)  Q4(h1, 20, 21, 22, 23)
        Q4(h2, 24, 25, 26, 27)  Q4(h3, 28, 29, 30, 31)
#undef Q4

        gxo[(size_t)t * GATES] = (a0 + a1) + (a2 + a3);     // coalesced b32
    }
}

// ======================= output projection =======================
__global__ void out_proj(const float* __restrict__ state1,
                         const float* __restrict__ Wout,
                         const float* __restrict__ bout,
                         float* __restrict__ out)
{
    const int b = blockIdx.x, j = threadIdx.x;
    __shared__ float sh[H];
    if (j < H) sh[j] = state1[b*2*H + j];
    __syncthreads();
    if (j < 4) {
        float a = bout[j];
        for (int k = 0; k < H; ++k) a = fmaf(Wout[j*H + k], sh[k], a);
        out[b*4 + j] = a;
    }
}

extern "C" void kernel_launch(void* const* d_in, const int* in_sizes, int n_in,
                              void* d_out, int out_size, void* d_ws, size_t ws_size,
                              hipStream_t stream)
{
    const float* x    = (const float*)d_in[0];
    const float* Wih0 = (const float*)d_in[1];
    const float* Whh0 = (const float*)d_in[2];
    const float* bih0 = (const float*)d_in[3];
    const float* bhh0 = (const float*)d_in[4];
    const float* Wih1 = (const float*)d_in[5];
    const float* Whh1 = (const float*)d_in[6];
    const float* bih1 = (const float*)d_in[7];
    const float* bhh1 = (const float*)d_in[8];
    const float* Wout = (const float*)d_in[9];
    const float* bout = (const float*)d_in[10];

    // ws layout: st0 | st1 | hs0 chunk | gx1 chunk  (tc >= TT for gemm grid)
    int tc = TT;
    for (int cand = TCMAX; cand >= TT; cand >>= 1) {
        size_t need = (size_t)2 * B_ * 2 * H * 4
                    + (size_t)B_ * cand * H * 4
                    + (size_t)B_ * cand * GATES * 4;
        if (need <= ws_size) { tc = cand; break; }
    }

    float* ws  = (float*)d_ws;
    float* st0 = ws;
    float* st1 = st0 + (size_t)B_ * 2 * H;
    float* hs0 = st1 + (size_t)B_ * 2 * H;
    float* gx1 = hs0 + (size_t)B_ * tc * H;

    const size_t shm_l0 = (size_t)(8 * 512 + H + tc * IN_) * 4;
    const size_t shm_l1 = (size_t)(8 * 512 + H) * 4;

    const int nchunks = T_ / tc;
    for (int c = 0; c < nchunks; ++c) {
        lstm_scan_l0<<<B_, 1024, shm_l0, stream>>>(
            x, Wih0, Whh0, bih0, bhh0, hs0, st0, tc, c);
        gx1_gemm<<<dim3(B_, tc / TT), 512, 0, stream>>>(
            hs0, Wih1, bih1, bhh1, gx1, tc);
        lstm_scan_l1<<<B_, 1024, shm_l1, stream>>>(gx1, Whh1, st1, tc, c);
    }
    out_proj<<<B_, 128, 0, stream>>>(st1, Wout, bout, (float*)d_out);
}